// Round 10
// baseline (105.707 us; speedup 1.0000x reference)
//
#include <hip/hip_runtime.h>
#include <math.h>

// Problem constants
constexpr int BN  = 16;    // batch
constexpr int HH  = 224;
constexpr int WW  = 224;
constexpr int CI  = 8;     // input channels
constexpr int FF  = 256;   // filter feature dim
constexpr int NC  = 16;    // output channels
constexpr int NP  = 1152;  // CI*NC*3*3 dynamic params per sample
// reference patch index p = cin*9 + dy*3 + dx ; w[b][p][c] = dyn[b][p*16+c]
// MFMA K-ordering: k = tap*8 + cin, tap = dy*3+dx (taps 9..11 pad=0)

typedef __attribute__((ext_vector_type(8))) short short8;   // 8 bf16 = 4 VGPR
typedef __attribute__((ext_vector_type(4))) float f32x4;

__device__ __forceinline__ float elu_f(float x) {
    return x > 0.0f ? x : (__expf(x) - 1.0f);
}

// split f32 -> bf16 hi (truncate) + bf16 lo (residual, truncate): v ~= hi+lo
__device__ __forceinline__ void split8(const float* v, short8& hi, short8& lo) {
#pragma unroll
    for (int j = 0; j < 8; ++j) {
        const unsigned u = __float_as_uint(v[j]);
        hi[j] = (short)(u >> 16);
        const float hf = __uint_as_float(u & 0xffff0000u);
        lo[j] = (short)(__float_as_uint(v[j] - hf) >> 16);
    }
}

// --------- fused kernel 1+2: h = elu(fi@W1+b1); dyn = h@Wd+bd; bias ----------
// grid 16 blocks (1 per sample), 256 threads. Validated in round 4.
__global__ __launch_bounds__(256) void k_hdyn(const float* __restrict__ fi,
                                              const float* __restrict__ W1,
                                              const float* __restrict__ b1,
                                              const float* __restrict__ Wd,
                                              const float* __restrict__ bd,
                                              const float* __restrict__ Wb,
                                              const float* __restrict__ bb,
                                              const float* __restrict__ dfn,
                                              float* __restrict__ w_out,
                                              float* __restrict__ bias_out) {
    __shared__ float xl[FF];
    __shared__ float hl[FF];
    const int b = blockIdx.x;
    const int t = threadIdx.x;               // 0..255

    xl[t] = fi[b * FF + t];
    __syncthreads();

    float acc = b1[t];
#pragma unroll 8
    for (int k = 0; k < FF; ++k) acc = fmaf(xl[k], W1[k * FF + t], acc);
    hl[t] = elu_f(acc);
    __syncthreads();

    // dyn columns: 1152 = 4*256 + 128
#pragma unroll 1
    for (int j = 0; j < 4; ++j) {
        const int i = j * 256 + t;
        float a = bd[i];
#pragma unroll 8
        for (int k = 0; k < FF; ++k) a = fmaf(hl[k], Wd[k * NP + i], a);
        w_out[b * NP + i] = a;
    }
    if (t < 128) {
        const int i = 1024 + t;
        float a = bd[i];
#pragma unroll 8
        for (int k = 0; k < FF; ++k) a = fmaf(hl[k], Wd[k * NP + i], a);
        w_out[b * NP + i] = a;
    }
    if (t < NC) {
        float a = bb[t] + dfn[t];
#pragma unroll 8
        for (int k = 0; k < FF; ++k) a = fmaf(hl[k], Wb[k * NC + t], a);
        bias_out[b * NC + t] = a;
    }
}

// ---------------- kernel 3: dynamic conv as per-sample MFMA GEMM -------------
// Round-8 validated body; grid split x2 for occupancy: each wave now does 7
// 16-px tiles (half a row) -> 3584 blocks x 2 waves = 7 waves/SIMD of TLP.
// mfma_f32_16x16x32_bf16 layouts (lane l):
//   A: row = l&15 (pixel), k = (l>>4)*8 + i  -> one 32B NHWC load per chunk
//   B: col = l&15 (channel), k = (l>>4)*8+i  -> loaded once per wave (24 regs)
//   C: col = l&15 (channel), row = (l>>4)*4 + r (pixel)
// Precision: bf16 hi/lo split, acc += hi*hi + lo*hi + hi*lo.
__global__ __launch_bounds__(128) void k_conv(const float* __restrict__ in,
                                              const float* __restrict__ w_all,
                                              const float* __restrict__ bias_all,
                                              float* __restrict__ out) {
    const int b    = blockIdx.z;
    const int half = blockIdx.x;       // 0/1: tiles 0-6 or 7-13
    const int t    = threadIdx.x;
    const int wid  = t >> 6;
    const int lane = t & 63;
    const int cl   = lane & 15;        // A-row pixel idx / B,C channel idx
    const int g    = lane >> 4;        // k-group 0..3
    const int y    = blockIdx.y * 2 + wid;

    // ---- per-lane tap geometry for the 3 k-chunks ----
    int  dyL[3], dxL[3];
    bool real[3];
#pragma unroll
    for (int c = 0; c < 3; ++c) {
        const int tap = c * 4 + g;
        real[c] = (tap < 9);
        const int tp = real[c] ? tap : 0;
        dyL[c] = tp / 3;
        dxL[c] = tp - 3 * dyL[c];
    }

    // ---- B fragments (hi/lo), loaded once per wave ----
    const float* __restrict__ wq = w_all + b * NP;
    short8 bhi0, blo0, bhi1, blo1, bhi2, blo2;
    {
        float wv[8];
#pragma unroll
        for (int i = 0; i < 8; ++i)
            wv[i] = real[0] ? wq[(i * 9 + (0 * 4 + g)) * NC + cl] : 0.0f;
        split8(wv, bhi0, blo0);
#pragma unroll
        for (int i = 0; i < 8; ++i)
            wv[i] = real[1] ? wq[(i * 9 + (1 * 4 + g)) * NC + cl] : 0.0f;
        split8(wv, bhi1, blo1);
#pragma unroll
        for (int i = 0; i < 8; ++i)
            wv[i] = real[2] ? wq[(i * 9 + (2 * 4 + g)) * NC + cl] : 0.0f;
        split8(wv, bhi2, blo2);
    }

    // ---- per-chunk input row base + validity ----
    size_t ro[3];
    bool   okr[3];
#pragma unroll
    for (int c = 0; c < 3; ++c) {
        const int iy = y + dyL[c] - 1;
        okr[c] = real[c] && ((unsigned)iy < (unsigned)HH);
        const int iyc = min(max(iy, 0), HH - 1);
        ro[c] = ((size_t)(b * HH + iyc) * WW) * CI;
    }

    const float bias = bias_all[b * NC + cl];
    const size_t orow = ((size_t)(b * HH + y) * WW) * NC;

#pragma unroll 1
    for (int tx = 0; tx < 7; ++tx) {
        const int x0 = (half * 7 + tx) * 16;
        f32x4 accM = {bias, bias, bias, bias};   // hi*hi
        f32x4 accC = {0.f, 0.f, 0.f, 0.f};       // corrections

#pragma unroll
        for (int c = 0; c < 3; ++c) {
            const int  ix = x0 + cl + dxL[c] - 1;
            const bool ok = okr[c] && ((unsigned)ix < (unsigned)WW);
            const int  ixc = min(max(ix, 0), WW - 1);
            const float4* pp = (const float4*)(in + ro[c] + (size_t)ixc * CI);
            const float4 a0 = pp[0];
            const float4 a1 = pp[1];
            float av[8];
            av[0] = ok ? a0.x : 0.0f;
            av[1] = ok ? a0.y : 0.0f;
            av[2] = ok ? a0.z : 0.0f;
            av[3] = ok ? a0.w : 0.0f;
            av[4] = ok ? a1.x : 0.0f;
            av[5] = ok ? a1.y : 0.0f;
            av[6] = ok ? a1.z : 0.0f;
            av[7] = ok ? a1.w : 0.0f;
            short8 ahi, alo;
            split8(av, ahi, alo);
            const short8 bh = (c == 0) ? bhi0 : (c == 1) ? bhi1 : bhi2;
            const short8 bl = (c == 0) ? blo0 : (c == 1) ? blo1 : blo2;
            accM = __builtin_amdgcn_mfma_f32_16x16x32_bf16(ahi, bh, accM, 0, 0, 0);
            accC = __builtin_amdgcn_mfma_f32_16x16x32_bf16(alo, bh, accC, 0, 0, 0);
            accC = __builtin_amdgcn_mfma_f32_16x16x32_bf16(ahi, bl, accC, 0, 0, 0);
        }

        // ---- epilogue: elu + store (lane cl = channel, rows g*4+r = pixel) --
#pragma unroll
        for (int r = 0; r < 4; ++r) {
            const int px = g * 4 + r;
            out[orow + (size_t)(x0 + px) * NC + cl] = elu_f(accM[r] + accC[r]);
        }
    }
}

extern "C" void kernel_launch(void* const* d_in, const int* in_sizes, int n_in,
                              void* d_out, int out_size, void* d_ws, size_t ws_size,
                              hipStream_t stream) {
    const float* inpt = (const float*)d_in[0];
    const float* fi   = (const float*)d_in[1];
    const float* W1   = (const float*)d_in[2];
    const float* b1   = (const float*)d_in[3];
    const float* Wd   = (const float*)d_in[4];
    const float* bd   = (const float*)d_in[5];
    const float* Wb   = (const float*)d_in[6];
    const float* bb   = (const float*)d_in[7];
    const float* dfn  = (const float*)d_in[8];
    float* out = (float*)d_out;

    float* ws    = (float*)d_ws;
    float* wDyn  = ws + 4096;             // 16*1152  = 18432 floats
    float* biasA = ws + 4096 + 18432;     // 16*16    = 256 floats

    k_hdyn<<<16, 256, 0, stream>>>(fi, W1, b1, Wd, bd, Wb, bb, dfn, wDyn, biasA);
    k_conv<<<dim3(2, 112, BN), 128, 0, stream>>>(inpt, wDyn, biasA, out);
}

// Round 11
// 49.701 us; speedup vs baseline: 2.1268x; 2.1268x over previous
//
#include <hip/hip_runtime.h>
#include <math.h>

// Problem constants
constexpr int BN  = 16;    // batch
constexpr int HH  = 224;
constexpr int WW  = 224;
constexpr int CI  = 8;     // input channels
constexpr int FF  = 256;   // filter feature dim
constexpr int NC  = 16;    // output channels
constexpr int NP  = 1152;  // CI*NC*3*3 dynamic params per sample
// reference patch index p = cin*9 + dy*3 + dx ; w[b][p][c] = dyn[b][p*16+c]
// MFMA K-ordering: k = tap*8 + cin, tap = dy*3+dx (taps 9..11 pad=0)

typedef __attribute__((ext_vector_type(8))) short short8;   // 8 bf16 = 4 VGPR
typedef __attribute__((ext_vector_type(4))) float f32x4;

__device__ __forceinline__ float elu_f(float x) {
    return x > 0.0f ? x : (__expf(x) - 1.0f);
}

// split f32 -> bf16 hi (truncate) + bf16 lo (residual, truncate): v ~= hi+lo
__device__ __forceinline__ void split8(const float* v, short8& hi, short8& lo) {
#pragma unroll
    for (int j = 0; j < 8; ++j) {
        const unsigned u = __float_as_uint(v[j]);
        hi[j] = (short)(u >> 16);
        const float hf = __uint_as_float(u & 0xffff0000u);
        lo[j] = (short)(__float_as_uint(v[j] - hf) >> 16);
    }
}

// ---------------- kernel 1: h = elu(filter_inpt @ W1 + b1) -------------------
// grid 32 blocks (16 samples x 2 halves), 128 threads  [proven ~5-8 us]
__global__ __launch_bounds__(128) void k_h(const float* __restrict__ fi,
                                           const float* __restrict__ W1,
                                           const float* __restrict__ b1,
                                           float* __restrict__ h_out) {
    __shared__ float x[FF];
    int bid = blockIdx.x;
    int b = bid >> 1, half = bid & 1;
    int t = threadIdx.x;
    x[t]       = fi[b * FF + t];
    x[t + 128] = fi[b * FF + t + 128];
    __syncthreads();
    int col = half * 128 + t;
    float acc = b1[col];
#pragma unroll 8
    for (int k = 0; k < FF; ++k) acc = fmaf(x[k], W1[k * FF + col], acc);
    h_out[b * FF + col] = elu_f(acc);
}

// ------------- kernel 2: dyn = h@Wd + bd ; bias = h@Wb + bb + dfn ------------
// grid 160 blocks (16 samples x 10 jobs), 128 threads  [proven ~13 us]
__global__ __launch_bounds__(128) void k_dyn(const float* __restrict__ h_in,
                                             const float* __restrict__ Wd,
                                             const float* __restrict__ bd,
                                             const float* __restrict__ Wb,
                                             const float* __restrict__ bb,
                                             const float* __restrict__ dfn,
                                             float* __restrict__ w_out,
                                             float* __restrict__ bias_out) {
    __shared__ float hl[FF];
    int bid = blockIdx.x;
    int b = bid / 10, j = bid % 10;
    int t = threadIdx.x;
    hl[t]       = h_in[b * FF + t];
    hl[t + 128] = h_in[b * FF + t + 128];
    __syncthreads();
    if (j < 9) {
        int i = j * 128 + t;          // i < 1152
        float acc = bd[i];
#pragma unroll 8
        for (int k = 0; k < FF; ++k) acc = fmaf(hl[k], Wd[k * NP + i], acc);
        w_out[b * NP + i] = acc;
    } else if (t < NC) {
        float acc = bb[t] + dfn[t];
        for (int k = 0; k < FF; ++k) acc = fmaf(hl[k], Wb[k * NC + t], acc);
        bias_out[b * NC + t] = acc;
    }
}

// ---------------- kernel 3: dynamic conv as per-sample MFMA GEMM -------------
// Round-8 validated body + 2x grid split (round 10: k_conv dropped out of the
// top-5 -> ~20 us). Each wave does 7 16-px tiles; 3584 blocks x 2 waves =
// 7 waves/SIMD of TLP.
// mfma_f32_16x16x32_bf16 layouts (lane l):
//   A: row = l&15 (pixel), k = (l>>4)*8 + i  -> one 32B NHWC load per chunk
//   B: col = l&15 (channel), k = (l>>4)*8+i  -> loaded once per wave (24 regs)
//   C: col = l&15 (channel), row = (l>>4)*4 + r (pixel)
// Precision: bf16 hi/lo split, acc += hi*hi + lo*hi + hi*lo.
__global__ __launch_bounds__(128) void k_conv(const float* __restrict__ in,
                                              const float* __restrict__ w_all,
                                              const float* __restrict__ bias_all,
                                              float* __restrict__ out) {
    const int b    = blockIdx.z;
    const int half = blockIdx.x;       // 0/1: tiles 0-6 or 7-13
    const int t    = threadIdx.x;
    const int wid  = t >> 6;
    const int lane = t & 63;
    const int cl   = lane & 15;        // A-row pixel idx / B,C channel idx
    const int g    = lane >> 4;        // k-group 0..3
    const int y    = blockIdx.y * 2 + wid;

    // ---- per-lane tap geometry for the 3 k-chunks ----
    int  dyL[3], dxL[3];
    bool real[3];
#pragma unroll
    for (int c = 0; c < 3; ++c) {
        const int tap = c * 4 + g;
        real[c] = (tap < 9);
        const int tp = real[c] ? tap : 0;
        dyL[c] = tp / 3;
        dxL[c] = tp - 3 * dyL[c];
    }

    // ---- B fragments (hi/lo), loaded once per wave ----
    const float* __restrict__ wq = w_all + b * NP;
    short8 bhi0, blo0, bhi1, blo1, bhi2, blo2;
    {
        float wv[8];
#pragma unroll
        for (int i = 0; i < 8; ++i)
            wv[i] = real[0] ? wq[(i * 9 + (0 * 4 + g)) * NC + cl] : 0.0f;
        split8(wv, bhi0, blo0);
#pragma unroll
        for (int i = 0; i < 8; ++i)
            wv[i] = real[1] ? wq[(i * 9 + (1 * 4 + g)) * NC + cl] : 0.0f;
        split8(wv, bhi1, blo1);
#pragma unroll
        for (int i = 0; i < 8; ++i)
            wv[i] = real[2] ? wq[(i * 9 + (2 * 4 + g)) * NC + cl] : 0.0f;
        split8(wv, bhi2, blo2);
    }

    // ---- per-chunk input row base + validity ----
    size_t ro[3];
    bool   okr[3];
#pragma unroll
    for (int c = 0; c < 3; ++c) {
        const int iy = y + dyL[c] - 1;
        okr[c] = real[c] && ((unsigned)iy < (unsigned)HH);
        const int iyc = min(max(iy, 0), HH - 1);
        ro[c] = ((size_t)(b * HH + iyc) * WW) * CI;
    }

    const float bias = bias_all[b * NC + cl];
    const size_t orow = ((size_t)(b * HH + y) * WW) * NC;

#pragma unroll 1
    for (int tx = 0; tx < 7; ++tx) {
        const int x0 = (half * 7 + tx) * 16;
        f32x4 accM = {bias, bias, bias, bias};   // hi*hi
        f32x4 accC = {0.f, 0.f, 0.f, 0.f};       // corrections

#pragma unroll
        for (int c = 0; c < 3; ++c) {
            const int  ix = x0 + cl + dxL[c] - 1;
            const bool ok = okr[c] && ((unsigned)ix < (unsigned)WW);
            const int  ixc = min(max(ix, 0), WW - 1);
            const float4* pp = (const float4*)(in + ro[c] + (size_t)ixc * CI);
            const float4 a0 = pp[0];
            const float4 a1 = pp[1];
            float av[8];
            av[0] = ok ? a0.x : 0.0f;
            av[1] = ok ? a0.y : 0.0f;
            av[2] = ok ? a0.z : 0.0f;
            av[3] = ok ? a0.w : 0.0f;
            av[4] = ok ? a1.x : 0.0f;
            av[5] = ok ? a1.y : 0.0f;
            av[6] = ok ? a1.z : 0.0f;
            av[7] = ok ? a1.w : 0.0f;
            short8 ahi, alo;
            split8(av, ahi, alo);
            const short8 bh = (c == 0) ? bhi0 : (c == 1) ? bhi1 : bhi2;
            const short8 bl = (c == 0) ? blo0 : (c == 1) ? blo1 : blo2;
            accM = __builtin_amdgcn_mfma_f32_16x16x32_bf16(ahi, bh, accM, 0, 0, 0);
            accC = __builtin_amdgcn_mfma_f32_16x16x32_bf16(alo, bh, accC, 0, 0, 0);
            accC = __builtin_amdgcn_mfma_f32_16x16x32_bf16(ahi, bl, accC, 0, 0, 0);
        }

        // ---- epilogue: elu + store (lane cl = channel, rows g*4+r = pixel) --
#pragma unroll
        for (int r = 0; r < 4; ++r) {
            const int px = g * 4 + r;
            out[orow + (size_t)(x0 + px) * NC + cl] = elu_f(accM[r] + accC[r]);
        }
    }
}

extern "C" void kernel_launch(void* const* d_in, const int* in_sizes, int n_in,
                              void* d_out, int out_size, void* d_ws, size_t ws_size,
                              hipStream_t stream) {
    const float* inpt = (const float*)d_in[0];
    const float* fi   = (const float*)d_in[1];
    const float* W1   = (const float*)d_in[2];
    const float* b1   = (const float*)d_in[3];
    const float* Wd   = (const float*)d_in[4];
    const float* bd   = (const float*)d_in[5];
    const float* Wb   = (const float*)d_in[6];
    const float* bb   = (const float*)d_in[7];
    const float* dfn  = (const float*)d_in[8];
    float* out = (float*)d_out;

    float* ws    = (float*)d_ws;
    float* h     = ws;                    // 16*256   = 4096 floats
    float* wDyn  = ws + 4096;             // 16*1152  = 18432 floats
    float* biasA = ws + 4096 + 18432;     // 16*16    = 256 floats

    k_h  <<<32, 128, 0, stream>>>(fi, W1, b1, h);
    k_dyn<<<160, 128, 0, stream>>>(h, Wd, bd, Wb, bb, dfn, wDyn, biasA);
    k_conv<<<dim3(2, 112, BN), 128, 0, stream>>>(inpt, wDyn, biasA, out);
}

// Round 12
// 45.880 us; speedup vs baseline: 2.3040x; 1.0833x over previous
//
#include <hip/hip_runtime.h>
#include <math.h>

// Problem constants
constexpr int BN  = 16;    // batch
constexpr int HH  = 224;
constexpr int WW  = 224;
constexpr int CI  = 8;     // input channels
constexpr int FF  = 256;   // filter feature dim
constexpr int NC  = 16;    // output channels
constexpr int NP  = 1152;  // CI*NC*3*3 dynamic params per sample
// reference patch index p = cin*9 + dy*3 + dx ; w[b][p][c] = dyn[b][p*16+c]
// MFMA K-ordering: k = tap*8 + cin, tap = dy*3+dx (taps 9..11 pad=0)

typedef __attribute__((ext_vector_type(8))) short short8;   // 8 bf16 = 4 VGPR
typedef __attribute__((ext_vector_type(4))) float f32x4;

__device__ __forceinline__ float elu_f(float x) {
    return x > 0.0f ? x : (__expf(x) - 1.0f);
}

// split f32 -> bf16 hi (truncate) + bf16 lo (residual, truncate): v ~= hi+lo
__device__ __forceinline__ void split8(const float* v, short8& hi, short8& lo) {
#pragma unroll
    for (int j = 0; j < 8; ++j) {
        const unsigned u = __float_as_uint(v[j]);
        hi[j] = (short)(u >> 16);
        const float hf = __uint_as_float(u & 0xffff0000u);
        lo[j] = (short)(__float_as_uint(v[j] - hf) >> 16);
    }
}

// ---------------- kernel 1: h = elu(filter_inpt @ W1 + b1) -------------------
// grid 32 blocks (16 samples x 2 halves), 128 threads. Also initializes
// w_out (=bd) and bias_out (=bb+dfn) for k_dyn's atomic k-split accumulation
// (stream order guarantees init completes before k_dyn's atomics).
__global__ __launch_bounds__(128) void k_h(const float* __restrict__ fi,
                                           const float* __restrict__ W1,
                                           const float* __restrict__ b1,
                                           const float* __restrict__ bd,
                                           const float* __restrict__ bb,
                                           const float* __restrict__ dfn,
                                           float* __restrict__ h_out,
                                           float* __restrict__ w_out,
                                           float* __restrict__ bias_out) {
    __shared__ float x[FF];
    int bid = blockIdx.x;
    int b = bid >> 1, half = bid & 1;
    int t = threadIdx.x;
    x[t]       = fi[b * FF + t];
    x[t + 128] = fi[b * FF + t + 128];
    __syncthreads();
    int col = half * 128 + t;
    float acc = b1[col];
#pragma unroll 8
    for (int k = 0; k < FF; ++k) acc = fmaf(x[k], W1[k * FF + col], acc);
    h_out[b * FF + col] = elu_f(acc);

    // ---- init for k_dyn atomics (grid-stride over 16*1152 + 256 values) ----
    const int gid = bid * 128 + t;           // 0..4095
    for (int i = gid; i < BN * NP; i += 4096) {
        const int c = i - (i / NP) * NP;
        w_out[i] = bd[c];
    }
    if (gid < BN * NC) bias_out[gid] = bb[gid & 15] + dfn[gid & 15];
}

// ------------- kernel 2: dyn += h@Wd ; bias += h@Wb (k-split atomics) --------
// grid 72 blocks = 9 col-groups (128 cols) x 8 k-splits (32 k), 128 threads.
// h-slice [16][32] staged in LDS (wave-uniform broadcast); each thread owns one
// Wd column: per k, ONE coalesced Wd load feeds 16 FMAs (one per sample).
// Wd is read exactly once chip-wide (was 16x). Partials combined via f32
// atomicAdd into the pre-initialized w_out/bias_out.
__global__ __launch_bounds__(128) void k_dyn(const float* __restrict__ h_in,
                                             const float* __restrict__ Wd,
                                             const float* __restrict__ Wb,
                                             float* __restrict__ w_out,
                                             float* __restrict__ bias_out) {
    __shared__ float hs[16][32];
    const int bid = blockIdx.x;
    const int cg  = bid % 9;                 // column group (128 cols)
    const int ks  = bid / 9;                 // k-split (32 k)
    const int k0  = ks * 32;
    const int t   = threadIdx.x;

#pragma unroll
    for (int j = 0; j < 4; ++j) {
        const int idx = t + 128 * j;         // 0..511
        const int bi = idx >> 5, kk = idx & 31;
        hs[bi][kk] = h_in[bi * FF + k0 + kk];
    }
    __syncthreads();

    const int i = cg * 128 + t;              // output column < 1152
    float a[16];
#pragma unroll
    for (int b = 0; b < 16; ++b) a[b] = 0.0f;

#pragma unroll 8
    for (int kk = 0; kk < 32; ++kk) {
        const float w = Wd[(size_t)(k0 + kk) * NP + i];
#pragma unroll
        for (int b = 0; b < 16; ++b) a[b] = fmaf(hs[b][kk], w, a[b]);
    }
#pragma unroll
    for (int b = 0; b < 16; ++b) atomicAdd(&w_out[b * NP + i], a[b]);

    if (cg == 0) {                           // bias partials ride along here
#pragma unroll
        for (int r = 0; r < 2; ++r) {
            const int p = t + r * 128;       // 0..255
            const int b = p >> 4, c = p & 15;
            float s = 0.0f;
#pragma unroll 8
            for (int kk = 0; kk < 32; ++kk)
                s = fmaf(hs[b][kk], Wb[(size_t)(k0 + kk) * NC + c], s);
            atomicAdd(&bias_out[b * NC + c], s);
        }
    }
}

// ---------------- kernel 3: dynamic conv as per-sample MFMA GEMM -------------
// Round-8 validated body + 2x grid split (round 10/11). Each wave does 7
// 16-px tiles; 3584 blocks x 2 waves = 7 waves/SIMD of TLP.
// mfma_f32_16x16x32_bf16 layouts (lane l):
//   A: row = l&15 (pixel), k = (l>>4)*8 + i  -> one 32B NHWC load per chunk
//   B: col = l&15 (channel), k = (l>>4)*8+i  -> loaded once per wave (24 regs)
//   C: col = l&15 (channel), row = (l>>4)*4 + r (pixel)
// Precision: bf16 hi/lo split, acc += hi*hi + lo*hi + hi*lo.
__global__ __launch_bounds__(128) void k_conv(const float* __restrict__ in,
                                              const float* __restrict__ w_all,
                                              const float* __restrict__ bias_all,
                                              float* __restrict__ out) {
    const int b    = blockIdx.z;
    const int half = blockIdx.x;       // 0/1: tiles 0-6 or 7-13
    const int t    = threadIdx.x;
    const int wid  = t >> 6;
    const int lane = t & 63;
    const int cl   = lane & 15;        // A-row pixel idx / B,C channel idx
    const int g    = lane >> 4;        // k-group 0..3
    const int y    = blockIdx.y * 2 + wid;

    // ---- per-lane tap geometry for the 3 k-chunks ----
    int  dyL[3], dxL[3];
    bool real[3];
#pragma unroll
    for (int c = 0; c < 3; ++c) {
        const int tap = c * 4 + g;
        real[c] = (tap < 9);
        const int tp = real[c] ? tap : 0;
        dyL[c] = tp / 3;
        dxL[c] = tp - 3 * dyL[c];
    }

    // ---- B fragments (hi/lo), loaded once per wave ----
    const float* __restrict__ wq = w_all + b * NP;
    short8 bhi0, blo0, bhi1, blo1, bhi2, blo2;
    {
        float wv[8];
#pragma unroll
        for (int i = 0; i < 8; ++i)
            wv[i] = real[0] ? wq[(i * 9 + (0 * 4 + g)) * NC + cl] : 0.0f;
        split8(wv, bhi0, blo0);
#pragma unroll
        for (int i = 0; i < 8; ++i)
            wv[i] = real[1] ? wq[(i * 9 + (1 * 4 + g)) * NC + cl] : 0.0f;
        split8(wv, bhi1, blo1);
#pragma unroll
        for (int i = 0; i < 8; ++i)
            wv[i] = real[2] ? wq[(i * 9 + (2 * 4 + g)) * NC + cl] : 0.0f;
        split8(wv, bhi2, blo2);
    }

    // ---- per-chunk input row base + validity ----
    size_t ro[3];
    bool   okr[3];
#pragma unroll
    for (int c = 0; c < 3; ++c) {
        const int iy = y + dyL[c] - 1;
        okr[c] = real[c] && ((unsigned)iy < (unsigned)HH);
        const int iyc = min(max(iy, 0), HH - 1);
        ro[c] = ((size_t)(b * HH + iyc) * WW) * CI;
    }

    const float bias = bias_all[b * NC + cl];
    const size_t orow = ((size_t)(b * HH + y) * WW) * NC;

#pragma unroll 1
    for (int tx = 0; tx < 7; ++tx) {
        const int x0 = (half * 7 + tx) * 16;
        f32x4 accM = {bias, bias, bias, bias};   // hi*hi
        f32x4 accC = {0.f, 0.f, 0.f, 0.f};       // corrections

#pragma unroll
        for (int c = 0; c < 3; ++c) {
            const int  ix = x0 + cl + dxL[c] - 1;
            const bool ok = okr[c] && ((unsigned)ix < (unsigned)WW);
            const int  ixc = min(max(ix, 0), WW - 1);
            const float4* pp = (const float4*)(in + ro[c] + (size_t)ixc * CI);
            const float4 a0 = pp[0];
            const float4 a1 = pp[1];
            float av[8];
            av[0] = ok ? a0.x : 0.0f;
            av[1] = ok ? a0.y : 0.0f;
            av[2] = ok ? a0.z : 0.0f;
            av[3] = ok ? a0.w : 0.0f;
            av[4] = ok ? a1.x : 0.0f;
            av[5] = ok ? a1.y : 0.0f;
            av[6] = ok ? a1.z : 0.0f;
            av[7] = ok ? a1.w : 0.0f;
            short8 ahi, alo;
            split8(av, ahi, alo);
            const short8 bh = (c == 0) ? bhi0 : (c == 1) ? bhi1 : bhi2;
            const short8 bl = (c == 0) ? blo0 : (c == 1) ? blo1 : blo2;
            accM = __builtin_amdgcn_mfma_f32_16x16x32_bf16(ahi, bh, accM, 0, 0, 0);
            accC = __builtin_amdgcn_mfma_f32_16x16x32_bf16(alo, bh, accC, 0, 0, 0);
            accC = __builtin_amdgcn_mfma_f32_16x16x32_bf16(ahi, bl, accC, 0, 0, 0);
        }

        // ---- epilogue: elu + store (lane cl = channel, rows g*4+r = pixel) --
#pragma unroll
        for (int r = 0; r < 4; ++r) {
            const int px = g * 4 + r;
            out[orow + (size_t)(x0 + px) * NC + cl] = elu_f(accM[r] + accC[r]);
        }
    }
}

extern "C" void kernel_launch(void* const* d_in, const int* in_sizes, int n_in,
                              void* d_out, int out_size, void* d_ws, size_t ws_size,
                              hipStream_t stream) {
    const float* inpt = (const float*)d_in[0];
    const float* fi   = (const float*)d_in[1];
    const float* W1   = (const float*)d_in[2];
    const float* b1   = (const float*)d_in[3];
    const float* Wd   = (const float*)d_in[4];
    const float* bd   = (const float*)d_in[5];
    const float* Wb   = (const float*)d_in[6];
    const float* bb   = (const float*)d_in[7];
    const float* dfn  = (const float*)d_in[8];
    float* out = (float*)d_out;

    float* ws    = (float*)d_ws;
    float* h     = ws;                    // 16*256   = 4096 floats
    float* wDyn  = ws + 4096;             // 16*1152  = 18432 floats
    float* biasA = ws + 4096 + 18432;     // 16*16    = 256 floats

    k_h  <<<32, 128, 0, stream>>>(fi, W1, b1, bd, bb, dfn, h, wDyn, biasA);
    k_dyn<<<72, 128, 0, stream>>>(h, Wd, Wb, wDyn, biasA);
    k_conv<<<dim3(2, 112, BN), 128, 0, stream>>>(inpt, wDyn, biasA, out);
}